// Round 1
// baseline (698.205 us; speedup 1.0000x reference)
//
#include <hip/hip_runtime.h>
#include <hip/hip_bf16.h>
#include <math.h>

// Problem constants
#define B_  4
#define L_  1024
#define HID_ 768
#define NH_ 12
#define D_  64
#define SCALE_ 0.125f          // 1/sqrt(64)
#define NEGV (-1e15f)

// ---------------------------------------------------------------------------
// SGEMM: C[M=4096, N=768] = A[4096,768] @ W[768,768] + bias, optional ReLU.
// W stored [in,out] row-major (as in reference). 64x64 tile, 16x16 threads,
// 4x4 microtile, BK=16.
// ---------------------------------------------------------------------------
__global__ __launch_bounds__(256) void sgemm_bias_kernel(
    const float* __restrict__ A, const float* __restrict__ W,
    const float* __restrict__ bias, float* __restrict__ C, int relu)
{
    const int N = 768, K = 768;
    __shared__ float As[16][68];   // [k][m], padded (row stride 272B, 16B-aligned)
    __shared__ float Bs[16][64];   // [k][n]

    const int tid = threadIdx.x;
    const int tx = tid & 15, ty = tid >> 4;
    const int m0 = blockIdx.x * 64;
    const int n0 = blockIdx.y * 64;

    // A load mapping: each thread loads float4 at (row=ar, k=ak..ak+3)
    const int ar = tid >> 2;            // 0..63
    const int ak = (tid & 3) * 4;       // 0,4,8,12
    // B load mapping: each thread loads float4 at (k=bk, n=bn..bn+3)
    const int bk = tid >> 4;            // 0..15
    const int bn = (tid & 15) * 4;      // 0..60

    float acc[4][4];
#pragma unroll
    for (int i = 0; i < 4; ++i)
#pragma unroll
        for (int j = 0; j < 4; ++j) acc[i][j] = 0.f;

    for (int k0 = 0; k0 < K; k0 += 16) {
        float4 av = *reinterpret_cast<const float4*>(&A[(size_t)(m0 + ar) * K + k0 + ak]);
        float4 bv = *reinterpret_cast<const float4*>(&W[(size_t)(k0 + bk) * N + n0 + bn]);
        As[ak + 0][ar] = av.x;
        As[ak + 1][ar] = av.y;
        As[ak + 2][ar] = av.z;
        As[ak + 3][ar] = av.w;
        *reinterpret_cast<float4*>(&Bs[bk][bn]) = bv;
        __syncthreads();
#pragma unroll
        for (int kk = 0; kk < 16; ++kk) {
            float4 a4 = *reinterpret_cast<const float4*>(&As[kk][ty * 4]);
            float4 b4 = *reinterpret_cast<const float4*>(&Bs[kk][tx * 4]);
            float a[4] = {a4.x, a4.y, a4.z, a4.w};
            float b[4] = {b4.x, b4.y, b4.z, b4.w};
#pragma unroll
            for (int i = 0; i < 4; ++i)
#pragma unroll
                for (int j = 0; j < 4; ++j) acc[i][j] += a[i] * b[j];
        }
        __syncthreads();
    }

    float4 bias4 = *reinterpret_cast<const float4*>(&bias[n0 + tx * 4]);
    float bb[4] = {bias4.x, bias4.y, bias4.z, bias4.w};
#pragma unroll
    for (int i = 0; i < 4; ++i) {
        float4 o;
        float v0 = acc[i][0] + bb[0];
        float v1 = acc[i][1] + bb[1];
        float v2 = acc[i][2] + bb[2];
        float v3 = acc[i][3] + bb[3];
        if (relu) { v0 = fmaxf(v0, 0.f); v1 = fmaxf(v1, 0.f); v2 = fmaxf(v2, 0.f); v3 = fmaxf(v3, 0.f); }
        o.x = v0; o.y = v1; o.z = v2; o.w = v3;
        *reinterpret_cast<float4*>(&C[(size_t)(m0 + ty * 4 + i) * N + n0 + tx * 4]) = o;
    }
}

// ---------------------------------------------------------------------------
// Fused flash-style attention with rel_pos bias + key mask.
// Q,K,V are row-major [B,L,HID] (= [B,L,NH,D]). Grid: (L/64, B*NH).
// Block 256 threads = 16x16, 4x4 microtile for both QK^T and PV.
// ---------------------------------------------------------------------------
__global__ __launch_bounds__(256) void attn_kernel(
    const float* __restrict__ Q, const float* __restrict__ K,
    const float* __restrict__ V, const float* __restrict__ rel,
    const int* __restrict__ seq_len, const int* __restrict__ lex_num,
    float* __restrict__ ctx)
{
    const int qt = blockIdx.x;           // 0..15
    const int bh = blockIdx.y;           // 0..47
    const int b = bh / NH_;
    const int h = bh % NH_;
    const int q0 = qt * 64;
    const int sl = seq_len[b] + lex_num[0];

    __shared__ float Qs[64][65];  // [d][q]
    __shared__ float Ks[64][65];  // [d][k]
    __shared__ float Vs[64][68];  // [k][d]
    __shared__ float Ps[64][68];  // [q][k]

    const int tid = threadIdx.x;
    const int tx = tid & 15, ty = tid >> 4;
    const int lr = tid >> 2;             // 0..63 (load row)
    const int lc = (tid & 3) * 16;       // 0,16,32,48 (load col base)

    // Load Q tile, pre-scaled, transposed to [d][q]
    {
        const float* qbase = Q + (size_t)(b * L_ + q0 + lr) * HID_ + h * D_ + lc;
#pragma unroll
        for (int j = 0; j < 4; ++j) {
            float4 t4 = *reinterpret_cast<const float4*>(qbase + j * 4);
            int d = lc + j * 4;
            Qs[d + 0][lr] = t4.x * SCALE_;
            Qs[d + 1][lr] = t4.y * SCALE_;
            Qs[d + 2][lr] = t4.z * SCALE_;
            Qs[d + 3][lr] = t4.w * SCALE_;
        }
    }

    float m_i[4], l_i[4], acc[4][4];
#pragma unroll
    for (int i = 0; i < 4; ++i) {
        m_i[i] = -INFINITY;
        l_i[i] = 0.f;
#pragma unroll
        for (int j = 0; j < 4; ++j) acc[i][j] = 0.f;
    }

    for (int kt = 0; kt < 16; ++kt) {
        __syncthreads();   // prev PV done reading Ks/Vs/Ps; Qs visible after 1st
        const int k0 = kt * 64;
        {
            const float* kbase = K + (size_t)(b * L_ + k0 + lr) * HID_ + h * D_ + lc;
            const float* vbase = V + (size_t)(b * L_ + k0 + lr) * HID_ + h * D_ + lc;
#pragma unroll
            for (int j = 0; j < 4; ++j) {
                float4 t4 = *reinterpret_cast<const float4*>(kbase + j * 4);
                int d = lc + j * 4;
                Ks[d + 0][lr] = t4.x;
                Ks[d + 1][lr] = t4.y;
                Ks[d + 2][lr] = t4.z;
                Ks[d + 3][lr] = t4.w;
                float4 v4 = *reinterpret_cast<const float4*>(vbase + j * 4);
                *reinterpret_cast<float4*>(&Vs[lr][lc + j * 4]) = v4;
            }
        }
        __syncthreads();

        // S tile = (Q*SCALE) @ K^T
        float s[4][4];
#pragma unroll
        for (int i = 0; i < 4; ++i)
#pragma unroll
            for (int j = 0; j < 4; ++j) s[i][j] = 0.f;
#pragma unroll 16
        for (int d = 0; d < 64; ++d) {
            float a[4], bv[4];
#pragma unroll
            for (int i = 0; i < 4; ++i) a[i] = Qs[d][ty * 4 + i];
#pragma unroll
            for (int j = 0; j < 4; ++j) bv[j] = Ks[d][tx * 4 + j];
#pragma unroll
            for (int i = 0; i < 4; ++i)
#pragma unroll
                for (int j = 0; j < 4; ++j) s[i][j] += a[i] * bv[j];
        }

        // + rel_pos, mask
#pragma unroll
        for (int i = 0; i < 4; ++i) {
            const float* rrow = rel + ((size_t)bh * L_ + q0 + ty * 4 + i) * L_ + k0 + tx * 4;
            float4 r4 = *reinterpret_cast<const float4*>(rrow);
            float rv[4] = {r4.x, r4.y, r4.z, r4.w};
#pragma unroll
            for (int j = 0; j < 4; ++j) {
                int col = k0 + tx * 4 + j;
                float val = s[i][j] + rv[j];
                s[i][j] = (col < sl) ? val : NEGV;
            }
        }

        // online softmax update (row groups = 16 lanes sharing ty)
#pragma unroll
        for (int i = 0; i < 4; ++i) {
            float rm = fmaxf(fmaxf(s[i][0], s[i][1]), fmaxf(s[i][2], s[i][3]));
            rm = fmaxf(rm, __shfl_xor(rm, 1, 16));
            rm = fmaxf(rm, __shfl_xor(rm, 2, 16));
            rm = fmaxf(rm, __shfl_xor(rm, 4, 16));
            rm = fmaxf(rm, __shfl_xor(rm, 8, 16));
            float mn = fmaxf(m_i[i], rm);
            float sc = expf(m_i[i] - mn);
            float rs = 0.f;
#pragma unroll
            for (int j = 0; j < 4; ++j) {
                float p = expf(s[i][j] - mn);
                s[i][j] = p;
                rs += p;
            }
            rs += __shfl_xor(rs, 1, 16);
            rs += __shfl_xor(rs, 2, 16);
            rs += __shfl_xor(rs, 4, 16);
            rs += __shfl_xor(rs, 8, 16);
            l_i[i] = l_i[i] * sc + rs;
            m_i[i] = mn;
#pragma unroll
            for (int j = 0; j < 4; ++j) acc[i][j] *= sc;
            *reinterpret_cast<float4*>(&Ps[ty * 4 + i][tx * 4]) =
                make_float4(s[i][0], s[i][1], s[i][2], s[i][3]);
        }
        __syncthreads();

        // PV accumulate: acc[i][:] += sum_k Ps[row_i][k] * Vs[k][tx*4..]
#pragma unroll 16
        for (int k = 0; k < 64; ++k) {
            float4 v4 = *reinterpret_cast<const float4*>(&Vs[k][tx * 4]);
#pragma unroll
            for (int i = 0; i < 4; ++i) {
                float p = Ps[ty * 4 + i][k];
                acc[i][0] += p * v4.x;
                acc[i][1] += p * v4.y;
                acc[i][2] += p * v4.z;
                acc[i][3] += p * v4.w;
            }
        }
    }

    // epilogue: normalize and store to ctx [B,L,HID]
#pragma unroll
    for (int i = 0; i < 4; ++i) {
        float invl = 1.f / l_i[i];
        float4 o = make_float4(acc[i][0] * invl, acc[i][1] * invl,
                               acc[i][2] * invl, acc[i][3] * invl);
        *reinterpret_cast<float4*>(
            &ctx[(size_t)(b * L_ + q0 + ty * 4 + i) * HID_ + h * D_ + tx * 4]) = o;
    }
}

// ---------------------------------------------------------------------------
// LayerNorm(2*x) over rows of 768. One block (256 thr) per row.
// ---------------------------------------------------------------------------
__global__ __launch_bounds__(256) void ln2_kernel(
    const float* __restrict__ in, const float* __restrict__ g,
    const float* __restrict__ bta, float* __restrict__ out)
{
    const int row = blockIdx.x;
    const float* x = in + (size_t)row * HID_;
    const int tid = threadIdx.x;

    float vals[3];
    float s = 0.f, ss = 0.f;
#pragma unroll
    for (int j = 0; j < 3; ++j) {
        float t = 2.f * x[tid + j * 256];
        vals[j] = t;
        s += t;
        ss += t * t;
    }
#pragma unroll
    for (int m = 1; m < 64; m <<= 1) {
        s += __shfl_xor(s, m, 64);
        ss += __shfl_xor(ss, m, 64);
    }
    __shared__ float sb[4], ssb[4];
    if ((tid & 63) == 0) { sb[tid >> 6] = s; ssb[tid >> 6] = ss; }
    __syncthreads();
    s = sb[0] + sb[1] + sb[2] + sb[3];
    ss = ssb[0] + ssb[1] + ssb[2] + ssb[3];
    const float mean = s * (1.f / 768.f);
    float var = ss * (1.f / 768.f) - mean * mean;
    if (var < 0.f) var = 0.f;
    const float inv = rsqrtf(var + 1e-5f);
#pragma unroll
    for (int j = 0; j < 3; ++j) {
        int c = tid + j * 256;
        out[(size_t)row * HID_ + c] = (vals[j] - mean) * inv * g[c] + bta[c];
    }
}

// ---------------------------------------------------------------------------
extern "C" void kernel_launch(void* const* d_in, const int* in_sizes, int n_in,
                              void* d_out, int out_size, void* d_ws, size_t ws_size,
                              hipStream_t stream) {
    const float* inp     = (const float*)d_in[0];
    const int*   seq_len = (const int*)d_in[1];
    const int*   lex_num = (const int*)d_in[2];
    const float* rel     = (const float*)d_in[3];
    const float* Wq = (const float*)d_in[4];
    const float* bq = (const float*)d_in[5];
    const float* Wk = (const float*)d_in[6];
    const float* bk = (const float*)d_in[7];
    const float* Wv = (const float*)d_in[8];
    const float* bv = (const float*)d_in[9];
    const float* Wo = (const float*)d_in[10];
    const float* bo = (const float*)d_in[11];
    const float* W0 = (const float*)d_in[12];
    const float* b0 = (const float*)d_in[13];
    const float* W1 = (const float*)d_in[14];
    const float* b1 = (const float*)d_in[15];
    const float* ln_g = (const float*)d_in[16];
    const float* ln_b = (const float*)d_in[17];
    float* out = (float*)d_out;

    float* ws = (float*)d_ws;
    const size_t NBUF = (size_t)B_ * L_ * HID_;   // 3,145,728 floats
    float* q   = ws + 0 * NBUF;
    float* k   = ws + 1 * NBUF;
    float* v   = ws + 2 * NBUF;
    float* ctx = ws + 3 * NBUF;
    // reuse: y=q, y2=k, hA=v, h2=ctx

    dim3 gblk(256);
    dim3 ggrid(64, 12);   // M/64 x N/64

    sgemm_bias_kernel<<<ggrid, gblk, 0, stream>>>(inp, Wq, bq, q, 0);
    sgemm_bias_kernel<<<ggrid, gblk, 0, stream>>>(inp, Wk, bk, k, 0);
    sgemm_bias_kernel<<<ggrid, gblk, 0, stream>>>(inp, Wv, bv, v, 0);

    attn_kernel<<<dim3(16, 48), gblk, 0, stream>>>(q, k, v, rel, seq_len, lex_num, ctx);

    // y = ctx @ Wo + bo   (into q)
    sgemm_bias_kernel<<<ggrid, gblk, 0, stream>>>(ctx, Wo, bo, q, 0);
    // y2 = LN(2*y)        (into k)
    ln2_kernel<<<dim3(4096), gblk, 0, stream>>>(q, ln_g, ln_b, k);
    // h = relu(y2 @ W0 + b0)  (into v)
    sgemm_bias_kernel<<<ggrid, gblk, 0, stream>>>(k, W0, b0, v, 1);
    // h2 = h @ W1 + b1    (into ctx)
    sgemm_bias_kernel<<<ggrid, gblk, 0, stream>>>(v, W1, b1, ctx, 0);
    // out = LN(2*h2)
    ln2_kernel<<<dim3(4096), gblk, 0, stream>>>(ctx, ln_g, ln_b, out);
}

// Round 2
// 210.318 us; speedup vs baseline: 3.3198x; 3.3198x over previous
//
#include <hip/hip_runtime.h>
#include <math.h>

#define B_   4
#define L_   1024
#define HID_ 768
#define NH_  12
#define D_   64
#define SCALE_ 0.125f
#define NEGV (-1e15f)

typedef __attribute__((ext_vector_type(4))) float  f32x4;
typedef __attribute__((ext_vector_type(8))) __bf16 bf16x8;
typedef __attribute__((ext_vector_type(8))) unsigned short ushort8v;
typedef __attribute__((ext_vector_type(4))) unsigned short ushort4v;

typedef const __attribute__((address_space(1))) unsigned int* gas1_t;
typedef __attribute__((address_space(3))) unsigned int*       las3_t;
#define GLDS16(g, l) __builtin_amdgcn_global_load_lds((gas1_t)(g), (las3_t)(l), 16, 0, 0)

static __device__ __forceinline__ unsigned short f2bf(float f) {
    unsigned int u = __builtin_bit_cast(unsigned int, f);
    u += 0x7fffu + ((u >> 16) & 1u);           // RNE
    return (unsigned short)(u >> 16);
}

// ---------------------------------------------------------------------------
// inp f32 -> bf16 (row-major kept). n4 = elems/4.
// ---------------------------------------------------------------------------
__global__ __launch_bounds__(256) void convert_x_kernel(
    const float* __restrict__ in, unsigned short* __restrict__ out, int n4)
{
    int i = blockIdx.x * 256 + threadIdx.x;
    if (i < n4) {
        float4 v = reinterpret_cast<const float4*>(in)[i];
        ushort4v o;
        o.x = f2bf(v.x); o.y = f2bf(v.y); o.z = f2bf(v.z); o.w = f2bf(v.w);
        reinterpret_cast<ushort4v*>(out)[i] = o;
    }
}

// ---------------------------------------------------------------------------
// W f32 [768 in][768 out] -> Wt bf16 [768 out][768 in]. grid (12,12,6).
// ---------------------------------------------------------------------------
struct WArgs { const float* w[6]; unsigned short* wt[6]; };

__global__ __launch_bounds__(256) void transpose_w_kernel(WArgs a)
{
    const float* W = a.w[blockIdx.z];
    unsigned short* Wt = a.wt[blockIdx.z];
    __shared__ float t[64][65];
    const int tid = threadIdx.x;
    const int lr = tid >> 2, lc4 = (tid & 3) * 16;
    const int r0 = blockIdx.y * 64, c0 = blockIdx.x * 64;
#pragma unroll
    for (int j = 0; j < 4; ++j) {
        float4 v = *reinterpret_cast<const float4*>(&W[(size_t)(r0 + lr) * HID_ + c0 + lc4 + j * 4]);
        t[lr][lc4 + j * 4 + 0] = v.x;
        t[lr][lc4 + j * 4 + 1] = v.y;
        t[lr][lc4 + j * 4 + 2] = v.z;
        t[lr][lc4 + j * 4 + 3] = v.w;
    }
    __syncthreads();
    unsigned short tmp[16];
#pragma unroll
    for (int j = 0; j < 16; ++j) tmp[j] = f2bf(t[lc4 + j][lr]);
    unsigned short* dst = &Wt[(size_t)(c0 + lr) * HID_ + r0 + lc4];
    *reinterpret_cast<ushort8v*>(dst)     = *reinterpret_cast<ushort8v*>(&tmp[0]);
    *reinterpret_cast<ushort8v*>(dst + 8) = *reinterpret_cast<ushort8v*>(&tmp[8]);
}

// ---------------------------------------------------------------------------
// bf16 GEMM: C[M=4096, 768] = A[4096,768] @ Wt^T + bias.
// A row-major [M][768] bf16, Wt row-major [768 out][768 in] bf16.
// 128x128 tile, BK=32, 4 waves (2x2), 4x4 fragments of 16x16x32 MFMA.
// mode 0: f32 C[m][n] ; mode 1: bf16 C[m][n] ; mode 2: bf16 Vt[(b*768+n)*1024+l]
// ---------------------------------------------------------------------------
struct GemmJob {
    const unsigned short* A;
    const unsigned short* Wt;
    const float* bias;
    void* C;
    int mode;
    int relu;
    float scale;
};
struct GemmArgs { GemmJob j[3]; };

__global__ __launch_bounds__(256) void gemm_bf16_kernel(GemmArgs args)
{
    const GemmJob jb = args.j[blockIdx.z];
    __shared__ unsigned short As[4096];   // [128][32] bf16, chunk-swizzled
    __shared__ unsigned short Bs[4096];

    const int tid = threadIdx.x;
    const int w = tid >> 6, lane = tid & 63, g = lane >> 4, lq = lane & 15;
    const int wr = w >> 1, wc = w & 1;
    const int m0 = blockIdx.x * 128, n0 = blockIdx.y * 128;

    f32x4 acc[4][4];
#pragma unroll
    for (int i = 0; i < 4; ++i)
#pragma unroll
        for (int j = 0; j < 4; ++j) acc[i][j] = (f32x4){0.f, 0.f, 0.f, 0.f};

    // staging chunk mapping (chunk c -> LDS byte c*16): r=c>>2, kq=(c&3)^((r>>1)&3)
    const int cA0 = tid,      rA0 = cA0 >> 2, kq0 = (cA0 & 3) ^ ((rA0 >> 1) & 3);
    const int cA1 = 256 + tid, rA1 = cA1 >> 2, kq1 = (cA1 & 3) ^ ((rA1 >> 1) & 3);
    const unsigned short* Ap0 = jb.A  + (size_t)(m0 + rA0) * HID_ + kq0 * 8;
    const unsigned short* Ap1 = jb.A  + (size_t)(m0 + rA1) * HID_ + kq1 * 8;
    const unsigned short* Bp0 = jb.Wt + (size_t)(n0 + rA0) * HID_ + kq0 * 8;
    const unsigned short* Bp1 = jb.Wt + (size_t)(n0 + rA1) * HID_ + kq1 * 8;
    char* AsB = (char*)As;
    char* BsB = (char*)Bs;
    const int wb = w * 1024;

    for (int k0 = 0; k0 < HID_; k0 += 32) {
        __syncthreads();
        GLDS16(Ap0 + k0, AsB + wb);
        GLDS16(Ap1 + k0, AsB + 4096 + wb);
        GLDS16(Bp0 + k0, BsB + wb);
        GLDS16(Bp1 + k0, BsB + 4096 + wb);
        __syncthreads();

        bf16x8 af[4], bf[4];
#pragma unroll
        for (int mi = 0; mi < 4; ++mi) {
            int row = wr * 64 + mi * 16 + lq;
            int kc = (g ^ ((row >> 1) & 3)) * 8;
            af[mi] = *reinterpret_cast<const bf16x8*>(&As[row * 32 + kc]);
        }
#pragma unroll
        for (int ni = 0; ni < 4; ++ni) {
            int row = wc * 64 + ni * 16 + lq;
            int kc = (g ^ ((row >> 1) & 3)) * 8;
            bf[ni] = *reinterpret_cast<const bf16x8*>(&Bs[row * 32 + kc]);
        }
#pragma unroll
        for (int mi = 0; mi < 4; ++mi)
#pragma unroll
            for (int ni = 0; ni < 4; ++ni)
                acc[mi][ni] = __builtin_amdgcn_mfma_f32_16x16x32_bf16(
                    af[mi], bf[ni], acc[mi][ni], 0, 0, 0);
    }

    float bcol[4];
#pragma unroll
    for (int ni = 0; ni < 4; ++ni) bcol[ni] = jb.bias[n0 + wc * 64 + ni * 16 + lq];

#pragma unroll
    for (int mi = 0; mi < 4; ++mi) {
#pragma unroll
        for (int ni = 0; ni < 4; ++ni) {
            const int n = n0 + wc * 64 + ni * 16 + lq;
            float v[4];
#pragma unroll
            for (int r = 0; r < 4; ++r) {
                float x = (acc[mi][ni][r] + bcol[ni]) * jb.scale;
                if (jb.relu) x = fmaxf(x, 0.f);
                v[r] = x;
            }
            const int mbase = m0 + wr * 64 + mi * 16 + 4 * g;
            if (jb.mode == 0) {
                float* C = (float*)jb.C;
#pragma unroll
                for (int r = 0; r < 4; ++r)
                    C[(size_t)(mbase + r) * HID_ + n] = v[r];
            } else if (jb.mode == 1) {
                unsigned short* C = (unsigned short*)jb.C;
#pragma unroll
                for (int r = 0; r < 4; ++r)
                    C[(size_t)(mbase + r) * HID_ + n] = f2bf(v[r]);
            } else {
                // Vt[(b*768 + n)*1024 + l], 4 consecutive tokens packed
                unsigned short* C = (unsigned short*)jb.C;
                const int bb = mbase >> 10, ltok = mbase & 1023;
                ushort4v o;
                o.x = f2bf(v[0]); o.y = f2bf(v[1]); o.z = f2bf(v[2]); o.w = f2bf(v[3]);
                *reinterpret_cast<ushort4v*>(&C[(size_t)(bb * HID_ + n) * L_ + ltok]) = o;
            }
        }
    }
}

// ---------------------------------------------------------------------------
// Flash attention, bf16 MFMA. Q pre-scaled. Vt layout [b][h][d][l].
// Grid (16 q-tiles, 48 bh), 256 thr = 4 waves, each wave owns 16 q-rows.
// ---------------------------------------------------------------------------
__global__ __launch_bounds__(256) void attn_mfma_kernel(
    const unsigned short* __restrict__ Qb, const unsigned short* __restrict__ Kb,
    const unsigned short* __restrict__ Vtb, const float* __restrict__ rel,
    const int* __restrict__ seq_len, const int* __restrict__ lex_num,
    unsigned short* __restrict__ ctx)
{
    const int qt = blockIdx.x, bh = blockIdx.y;
    const int b = bh / NH_, h = bh % NH_;
    const int q0 = qt * 64;
    const int sl = seq_len[b] + lex_num[0];

    __shared__ unsigned short Qs[64 * 72];
    __shared__ unsigned short Ks[64 * 72];
    __shared__ unsigned short Vs[64 * 72];   // transposed: [d][kv]
    __shared__ unsigned short Ps[64 * 72];

    const int tid = threadIdx.x;
    const int w = tid >> 6, lane = tid & 63, g = lane >> 4, lq = lane & 15;

    // stage Q tile [64 q][64 d]
#pragma unroll
    for (int j = 0; j < 2; ++j) {
        int c = j * 256 + tid, r = c >> 3, cc = c & 7;
        *reinterpret_cast<ushort8v*>(&Qs[r * 72 + cc * 8]) =
            *reinterpret_cast<const ushort8v*>(&Qb[(size_t)(b * L_ + q0 + r) * HID_ + h * D_ + cc * 8]);
    }

    f32x4 acc[4];
    float m_r[4], l_r[4];
#pragma unroll
    for (int i = 0; i < 4; ++i) {
        acc[i] = (f32x4){0.f, 0.f, 0.f, 0.f};
        m_r[i] = -3e38f; l_r[i] = 0.f;
    }

    for (int kt = 0; kt < 16; ++kt) {
        const int k0 = kt * 64;
        __syncthreads();
#pragma unroll
        for (int j = 0; j < 2; ++j) {
            int c = j * 256 + tid, r = c >> 3, cc = c & 7;
            *reinterpret_cast<ushort8v*>(&Ks[r * 72 + cc * 8]) =
                *reinterpret_cast<const ushort8v*>(&Kb[(size_t)(b * L_ + k0 + r) * HID_ + h * D_ + cc * 8]);
            *reinterpret_cast<ushort8v*>(&Vs[r * 72 + cc * 8]) =
                *reinterpret_cast<const ushort8v*>(&Vtb[(size_t)(b * HID_ + h * D_ + r) * L_ + k0 + cc * 8]);
        }
        __syncthreads();

        // S strip = Q strip @ K^T  (4 col-fragments)
        f32x4 s[4];
#pragma unroll
        for (int ni = 0; ni < 4; ++ni) s[ni] = (f32x4){0.f, 0.f, 0.f, 0.f};
#pragma unroll
        for (int ks = 0; ks < 2; ++ks) {
            bf16x8 aq = *reinterpret_cast<const bf16x8*>(&Qs[(w * 16 + lq) * 72 + ks * 32 + g * 8]);
#pragma unroll
            for (int ni = 0; ni < 4; ++ni) {
                bf16x8 bk = *reinterpret_cast<const bf16x8*>(&Ks[(ni * 16 + lq) * 72 + ks * 32 + g * 8]);
                s[ni] = __builtin_amdgcn_mfma_f32_16x16x32_bf16(aq, bk, s[ni], 0, 0, 0);
            }
        }

        // rel bias + mask
        float sv[4][4];
#pragma unroll
        for (int ni = 0; ni < 4; ++ni) {
            const int col = k0 + ni * 16 + lq;
            const bool ok = col < sl;
            const float* rp = rel + (size_t)bh * (L_ * L_) + (size_t)(q0 + w * 16 + 4 * g) * L_ + col;
#pragma unroll
            for (int r = 0; r < 4; ++r) {
                float rv = rp[(size_t)r * L_];
                sv[ni][r] = ok ? (s[ni][r] + rv) : NEGV;
            }
        }

        // online softmax per row (16 lanes share a row)
#pragma unroll
        for (int r = 0; r < 4; ++r) {
            float rm = fmaxf(fmaxf(sv[0][r], sv[1][r]), fmaxf(sv[2][r], sv[3][r]));
            rm = fmaxf(rm, __shfl_xor(rm, 1, 16));
            rm = fmaxf(rm, __shfl_xor(rm, 2, 16));
            rm = fmaxf(rm, __shfl_xor(rm, 4, 16));
            rm = fmaxf(rm, __shfl_xor(rm, 8, 16));
            float mn = fmaxf(m_r[r], rm);
            float sc = __expf(m_r[r] - mn);
            float p[4], rs = 0.f;
#pragma unroll
            for (int ni = 0; ni < 4; ++ni) {
                p[ni] = __expf(sv[ni][r] - mn);
                rs += p[ni];
            }
            rs += __shfl_xor(rs, 1, 16);
            rs += __shfl_xor(rs, 2, 16);
            rs += __shfl_xor(rs, 4, 16);
            rs += __shfl_xor(rs, 8, 16);
            l_r[r] = l_r[r] * sc + rs;
            m_r[r] = mn;
#pragma unroll
            for (int ni = 0; ni < 4; ++ni) {
                acc[ni][r] *= sc;
                Ps[(w * 16 + 4 * g + r) * 72 + ni * 16 + lq] = f2bf(p[ni]);
            }
        }

        // O strip += P strip @ V tile
#pragma unroll
        for (int ks = 0; ks < 2; ++ks) {
            bf16x8 ap = *reinterpret_cast<const bf16x8*>(&Ps[(w * 16 + lq) * 72 + ks * 32 + g * 8]);
#pragma unroll
            for (int ni = 0; ni < 4; ++ni) {
                bf16x8 bv = *reinterpret_cast<const bf16x8*>(&Vs[(ni * 16 + lq) * 72 + ks * 32 + g * 8]);
                acc[ni] = __builtin_amdgcn_mfma_f32_16x16x32_bf16(ap, bv, acc[ni], 0, 0, 0);
            }
        }
    }

    // epilogue
    float inv[4];
#pragma unroll
    for (int r = 0; r < 4; ++r) inv[r] = 1.f / l_r[r];
#pragma unroll
    for (int ni = 0; ni < 4; ++ni)
#pragma unroll
        for (int r = 0; r < 4; ++r)
            ctx[(size_t)(b * L_ + q0 + w * 16 + 4 * g + r) * HID_ + h * D_ + ni * 16 + lq] =
                f2bf(acc[ni][r] * inv[r]);
}

// ---------------------------------------------------------------------------
// LayerNorm(2*x) over rows of 768; out f32 or bf16.
// ---------------------------------------------------------------------------
__global__ __launch_bounds__(256) void ln2_kernel(
    const float* __restrict__ in, const float* __restrict__ g,
    const float* __restrict__ bta, void* __restrict__ out, int bf16out)
{
    const int row = blockIdx.x;
    const float* x = in + (size_t)row * HID_;
    const int tid = threadIdx.x;

    float vals[3];
    float s = 0.f, ss = 0.f;
#pragma unroll
    for (int j = 0; j < 3; ++j) {
        float t = 2.f * x[tid + j * 256];
        vals[j] = t;
        s += t;
        ss += t * t;
    }
#pragma unroll
    for (int m = 1; m < 64; m <<= 1) {
        s += __shfl_xor(s, m, 64);
        ss += __shfl_xor(ss, m, 64);
    }
    __shared__ float sb[4], ssb[4];
    if ((tid & 63) == 0) { sb[tid >> 6] = s; ssb[tid >> 6] = ss; }
    __syncthreads();
    s = sb[0] + sb[1] + sb[2] + sb[3];
    ss = ssb[0] + ssb[1] + ssb[2] + ssb[3];
    const float mean = s * (1.f / 768.f);
    float var = ss * (1.f / 768.f) - mean * mean;
    if (var < 0.f) var = 0.f;
    const float invs = rsqrtf(var + 1e-5f);
    if (bf16out) {
        unsigned short* o = (unsigned short*)out;
#pragma unroll
        for (int j = 0; j < 3; ++j) {
            int c = tid + j * 256;
            o[(size_t)row * HID_ + c] = f2bf((vals[j] - mean) * invs * g[c] + bta[c]);
        }
    } else {
        float* o = (float*)out;
#pragma unroll
        for (int j = 0; j < 3; ++j) {
            int c = tid + j * 256;
            o[(size_t)row * HID_ + c] = (vals[j] - mean) * invs * g[c] + bta[c];
        }
    }
}

// ---------------------------------------------------------------------------
extern "C" void kernel_launch(void* const* d_in, const int* in_sizes, int n_in,
                              void* d_out, int out_size, void* d_ws, size_t ws_size,
                              hipStream_t stream) {
    const float* inp     = (const float*)d_in[0];
    const int*   seq_len = (const int*)d_in[1];
    const int*   lex_num = (const int*)d_in[2];
    const float* rel     = (const float*)d_in[3];
    const float* Wq = (const float*)d_in[4];
    const float* bq = (const float*)d_in[5];
    const float* Wk = (const float*)d_in[6];
    const float* bk = (const float*)d_in[7];
    const float* Wv = (const float*)d_in[8];
    const float* bv = (const float*)d_in[9];
    const float* Wo = (const float*)d_in[10];
    const float* bo = (const float*)d_in[11];
    const float* W0 = (const float*)d_in[12];
    const float* b0 = (const float*)d_in[13];
    const float* W1 = (const float*)d_in[14];
    const float* b1 = (const float*)d_in[15];
    const float* ln_g = (const float*)d_in[16];
    const float* ln_b = (const float*)d_in[17];
    float* out = (float*)d_out;

    // ---- workspace carve (bytes) ----
    char* W = (char*)d_ws;
    const size_t WT_SZ = (size_t)HID_ * HID_ * 2;          // 1,179,648
    unsigned short* Wt[6];
    for (int i = 0; i < 6; ++i) Wt[i] = (unsigned short*)(W + i * WT_SZ);
    size_t off = 6 * WT_SZ;                                 // 7,077,888
    const size_t TOK_BF = (size_t)B_ * L_ * HID_ * 2;       // 6,291,456
    unsigned short* qb  = (unsigned short*)(W + off); off += TOK_BF;
    unsigned short* kb  = (unsigned short*)(W + off); off += TOK_BF;
    unsigned short* vtb = (unsigned short*)(W + off); off += TOK_BF;  // later y2b
    unsigned short* Eb  = (unsigned short*)(W + off); off += TOK_BF;  // Xb then ctxb
    float* Fbuf = (float*)(W + off);                        // y then h2 (12.58 MB)

    unsigned short* Xb   = Eb;
    unsigned short* ctxb = Eb;
    unsigned short* y2b  = vtb;
    unsigned short* hb   = qb;

    // 1. convert inp -> bf16
    convert_x_kernel<<<dim3(3072), dim3(256), 0, stream>>>(inp, Xb, (B_ * L_ * HID_) / 4);

    // 2. transpose+convert weights
    {
        WArgs wa;
        const float* ws_[6] = {Wq, Wk, Wv, Wo, W0, W1};
        for (int i = 0; i < 6; ++i) { wa.w[i] = ws_[i]; wa.wt[i] = Wt[i]; }
        transpose_w_kernel<<<dim3(12, 12, 6), dim3(256), 0, stream>>>(wa);
    }

    // 3. QKV fused GEMM
    {
        GemmArgs ga;
        ga.j[0] = {Xb, Wt[0], bq, (void*)qb,  1, 0, SCALE_};  // Q, pre-scaled
        ga.j[1] = {Xb, Wt[1], bk, (void*)kb,  1, 0, 1.f};     // K
        ga.j[2] = {Xb, Wt[2], bv, (void*)vtb, 2, 0, 1.f};     // V, transposed store
        gemm_bf16_kernel<<<dim3(32, 6, 3), dim3(256), 0, stream>>>(ga);
    }

    // 4. attention
    attn_mfma_kernel<<<dim3(16, 48), dim3(256), 0, stream>>>(
        qb, kb, vtb, rel, seq_len, lex_num, ctxb);

    // 5. y = ctx @ Wo + bo  (f32 into Fbuf)
    {
        GemmArgs ga;
        ga.j[0] = {ctxb, Wt[3], bo, (void*)Fbuf, 0, 0, 1.f};
        gemm_bf16_kernel<<<dim3(32, 6, 1), dim3(256), 0, stream>>>(ga);
    }
    // 6. y2 = LN(2y) -> bf16
    ln2_kernel<<<dim3(4096), dim3(256), 0, stream>>>(Fbuf, ln_g, ln_b, (void*)y2b, 1);
    // 7. h = relu(y2 @ W0 + b0) -> bf16
    {
        GemmArgs ga;
        ga.j[0] = {y2b, Wt[4], b0, (void*)hb, 1, 1, 1.f};
        gemm_bf16_kernel<<<dim3(32, 6, 1), dim3(256), 0, stream>>>(ga);
    }
    // 8. h2 = h @ W1 + b1 -> f32
    {
        GemmArgs ga;
        ga.j[0] = {hb, Wt[5], b1, (void*)Fbuf, 0, 0, 1.f};
        gemm_bf16_kernel<<<dim3(32, 6, 1), dim3(256), 0, stream>>>(ga);
    }
    // 9. out = LN(2*h2) -> f32
    ln2_kernel<<<dim3(4096), dim3(256), 0, stream>>>(Fbuf, ln_g, ln_b, (void*)out, 0);
}

// Round 3
// 151.750 us; speedup vs baseline: 4.6010x; 1.3860x over previous
//
#include <hip/hip_runtime.h>
#include <math.h>

#define B_   4
#define L_   1024
#define HID_ 768
#define NH_  12
#define D_   64
#define SCALE_ 0.125f
#define NEGV (-1e15f)

typedef __attribute__((ext_vector_type(4))) float  f32x4;
typedef __attribute__((ext_vector_type(8))) __bf16 bf16x8;
typedef __attribute__((ext_vector_type(8))) unsigned short ushort8v;
typedef __attribute__((ext_vector_type(4))) unsigned short ushort4v;

typedef const __attribute__((address_space(1))) unsigned int* gas1_t;
typedef __attribute__((address_space(3))) unsigned int*       las3_t;
#define GLDS16(g, l) __builtin_amdgcn_global_load_lds((gas1_t)(g), (las3_t)(l), 16, 0, 0)

static __device__ __forceinline__ unsigned short f2bf(float f) {
    unsigned int u = __builtin_bit_cast(unsigned int, f);
    u += 0x7fffu + ((u >> 16) & 1u);           // RNE
    return (unsigned short)(u >> 16);
}

// ---------------------------------------------------------------------------
// inp f32 -> bf16 (row-major kept). n4 = elems/4.
// ---------------------------------------------------------------------------
__global__ __launch_bounds__(256) void convert_x_kernel(
    const float* __restrict__ in, unsigned short* __restrict__ out, int n4)
{
    int i = blockIdx.x * 256 + threadIdx.x;
    if (i < n4) {
        float4 v = reinterpret_cast<const float4*>(in)[i];
        ushort4v o;
        o.x = f2bf(v.x); o.y = f2bf(v.y); o.z = f2bf(v.z); o.w = f2bf(v.w);
        reinterpret_cast<ushort4v*>(out)[i] = o;
    }
}

// ---------------------------------------------------------------------------
// W f32 [768 in][768 out] -> Wt bf16 [768 out][768 in]. grid (12,12,6).
// ---------------------------------------------------------------------------
struct WArgs { const float* w[6]; unsigned short* wt[6]; };

__global__ __launch_bounds__(256) void transpose_w_kernel(WArgs a)
{
    const float* W = a.w[blockIdx.z];
    unsigned short* Wt = a.wt[blockIdx.z];
    __shared__ float t[64][65];
    const int tid = threadIdx.x;
    const int lr = tid >> 2, lc4 = (tid & 3) * 16;
    const int r0 = blockIdx.y * 64, c0 = blockIdx.x * 64;
#pragma unroll
    for (int j = 0; j < 4; ++j) {
        float4 v = *reinterpret_cast<const float4*>(&W[(size_t)(r0 + lr) * HID_ + c0 + lc4 + j * 4]);
        t[lr][lc4 + j * 4 + 0] = v.x;
        t[lr][lc4 + j * 4 + 1] = v.y;
        t[lr][lc4 + j * 4 + 2] = v.z;
        t[lr][lc4 + j * 4 + 3] = v.w;
    }
    __syncthreads();
    unsigned short tmp[16];
#pragma unroll
    for (int j = 0; j < 16; ++j) tmp[j] = f2bf(t[lc4 + j][lr]);
    unsigned short* dst = &Wt[(size_t)(c0 + lr) * HID_ + r0 + lc4];
    *reinterpret_cast<ushort8v*>(dst)     = *reinterpret_cast<ushort8v*>(&tmp[0]);
    *reinterpret_cast<ushort8v*>(dst + 8) = *reinterpret_cast<ushort8v*>(&tmp[8]);
}

// ---------------------------------------------------------------------------
// bf16 GEMM: C[M=4096, 768] = A[4096,768] @ Wt^T + bias.
// 128x128 tile, BK=32, 4 waves (2x2), 4x4 fragments of 16x16x32 MFMA.
// mode 0: f32 C[m][n] ; mode 1: bf16 C[m][n] ; mode 2: bf16 Vt[(b*768+n)*1024+l]
// ---------------------------------------------------------------------------
struct GemmJob {
    const unsigned short* A;
    const unsigned short* Wt;
    const float* bias;
    void* C;
    int mode;
    int relu;
    float scale;
};
struct GemmArgs { GemmJob j[3]; };

__global__ __launch_bounds__(256) void gemm_bf16_kernel(GemmArgs args)
{
    const GemmJob jb = args.j[blockIdx.z];
    __shared__ unsigned short As[4096];   // [128][32] bf16, chunk-swizzled
    __shared__ unsigned short Bs[4096];

    const int tid = threadIdx.x;
    const int w = tid >> 6, lane = tid & 63, g = lane >> 4, lq = lane & 15;
    const int wr = w >> 1, wc = w & 1;
    const int m0 = blockIdx.x * 128, n0 = blockIdx.y * 128;

    f32x4 acc[4][4];
#pragma unroll
    for (int i = 0; i < 4; ++i)
#pragma unroll
        for (int j = 0; j < 4; ++j) acc[i][j] = (f32x4){0.f, 0.f, 0.f, 0.f};

    const int cA0 = tid,       rA0 = cA0 >> 2, kq0 = (cA0 & 3) ^ ((rA0 >> 1) & 3);
    const int cA1 = 256 + tid, rA1 = cA1 >> 2, kq1 = (cA1 & 3) ^ ((rA1 >> 1) & 3);
    const unsigned short* Ap0 = jb.A  + (size_t)(m0 + rA0) * HID_ + kq0 * 8;
    const unsigned short* Ap1 = jb.A  + (size_t)(m0 + rA1) * HID_ + kq1 * 8;
    const unsigned short* Bp0 = jb.Wt + (size_t)(n0 + rA0) * HID_ + kq0 * 8;
    const unsigned short* Bp1 = jb.Wt + (size_t)(n0 + rA1) * HID_ + kq1 * 8;
    char* AsB = (char*)As;
    char* BsB = (char*)Bs;
    const int wb = w * 1024;

    for (int k0 = 0; k0 < HID_; k0 += 32) {
        __syncthreads();
        GLDS16(Ap0 + k0, AsB + wb);
        GLDS16(Ap1 + k0, AsB + 4096 + wb);
        GLDS16(Bp0 + k0, BsB + wb);
        GLDS16(Bp1 + k0, BsB + 4096 + wb);
        __syncthreads();

        bf16x8 af[4], bf[4];
#pragma unroll
        for (int mi = 0; mi < 4; ++mi) {
            int row = wr * 64 + mi * 16 + lq;
            int kc = (g ^ ((row >> 1) & 3)) * 8;
            af[mi] = *reinterpret_cast<const bf16x8*>(&As[row * 32 + kc]);
        }
#pragma unroll
        for (int ni = 0; ni < 4; ++ni) {
            int row = wc * 64 + ni * 16 + lq;
            int kc = (g ^ ((row >> 1) & 3)) * 8;
            bf[ni] = *reinterpret_cast<const bf16x8*>(&Bs[row * 32 + kc]);
        }
#pragma unroll
        for (int mi = 0; mi < 4; ++mi)
#pragma unroll
            for (int ni = 0; ni < 4; ++ni)
                acc[mi][ni] = __builtin_amdgcn_mfma_f32_16x16x32_bf16(
                    af[mi], bf[ni], acc[mi][ni], 0, 0, 0);
    }

    float bcol[4];
#pragma unroll
    for (int ni = 0; ni < 4; ++ni) bcol[ni] = jb.bias[n0 + wc * 64 + ni * 16 + lq];

#pragma unroll
    for (int mi = 0; mi < 4; ++mi) {
#pragma unroll
        for (int ni = 0; ni < 4; ++ni) {
            const int n = n0 + wc * 64 + ni * 16 + lq;
            float v[4];
#pragma unroll
            for (int r = 0; r < 4; ++r) {
                float x = (acc[mi][ni][r] + bcol[ni]) * jb.scale;
                if (jb.relu) x = fmaxf(x, 0.f);
                v[r] = x;
            }
            const int mbase = m0 + wr * 64 + mi * 16 + 4 * g;
            if (jb.mode == 0) {
                float* C = (float*)jb.C;
#pragma unroll
                for (int r = 0; r < 4; ++r)
                    C[(size_t)(mbase + r) * HID_ + n] = v[r];
            } else if (jb.mode == 1) {
                unsigned short* C = (unsigned short*)jb.C;
#pragma unroll
                for (int r = 0; r < 4; ++r)
                    C[(size_t)(mbase + r) * HID_ + n] = f2bf(v[r]);
            } else {
                unsigned short* C = (unsigned short*)jb.C;
                const int bb = mbase >> 10, ltok = mbase & 1023;
                ushort4v o;
                o.x = f2bf(v[0]); o.y = f2bf(v[1]); o.z = f2bf(v[2]); o.w = f2bf(v[3]);
                *reinterpret_cast<ushort4v*>(&C[(size_t)(bb * HID_ + n) * L_ + ltok]) = o;
            }
        }
    }
}

// ---------------------------------------------------------------------------
// Flash attention, bf16 MFMA, deep-pipelined:
//  - skips fully-masked key tiles (k0 >= seq_len+lex_num)
//  - K/V double-buffered in LDS, reg-staged one tile ahead
//  - rel_pos prefetched one tile ahead into registers
//  - Q held in registers; ONE barrier per key tile
// Q pre-scaled. Vt layout [b][h][d][l]. Grid (16, 48), 256 thr = 4 waves.
// ---------------------------------------------------------------------------
__global__ __launch_bounds__(256) void attn_mfma_kernel(
    const unsigned short* __restrict__ Qb, const unsigned short* __restrict__ Kb,
    const unsigned short* __restrict__ Vtb, const float* __restrict__ rel,
    const int* __restrict__ seq_len, const int* __restrict__ lex_num,
    unsigned short* __restrict__ ctx)
{
    const int qt = blockIdx.x, bh = blockIdx.y;
    const int b = bh / NH_, h = bh % NH_;
    const int q0 = qt * 64;
    const int sl = seq_len[b] + lex_num[0];
    const int nkt = (sl + 63) >> 6;          // only tiles with >=1 valid col

    __shared__ unsigned short Ks[2][64 * 72];
    __shared__ unsigned short Vs[2][64 * 72];
    __shared__ unsigned short Ps[64 * 72];

    const int tid = threadIdx.x;
    const int w = tid >> 6, lane = tid & 63, g = lane >> 4, lq = lane & 15;

    // staging map: chunk c in [0,512): row r=c>>3, col-chunk cc=c&7 (8 elems)
    const int r0 = tid >> 3,        cc0 = tid & 7;
    const int r1 = 32 + (tid >> 3), cc1 = tid & 7;
    const unsigned short* Kbase = Kb  + (size_t)(b * L_) * HID_ + h * D_;
    const unsigned short* Vbase = Vtb + (size_t)(b * HID_ + h * D_) * L_;

    // Q fragments in registers (rows w*16+lq)
    bf16x8 aq[2];
#pragma unroll
    for (int ks = 0; ks < 2; ++ks)
        aq[ks] = *reinterpret_cast<const bf16x8*>(
            &Qb[(size_t)(b * L_ + q0 + w * 16 + lq) * HID_ + h * D_ + ks * 32 + g * 8]);

    // rel base for this thread's 4 fragment rows (q0 + w*16 + 4g + r)
    const float* relbase = rel + (size_t)bh * (L_ * L_) + (size_t)(q0 + w * 16 + 4 * g) * L_ + lq;

    f32x4 acc[4];
    float m_r[4], l_r[4];
#pragma unroll
    for (int i = 0; i < 4; ++i) {
        acc[i] = (f32x4){0.f, 0.f, 0.f, 0.f};
        m_r[i] = -3e38f; l_r[i] = 0.f;
    }

    // prologue: stage tile 0 into regs
    ushort8v kreg0, kreg1, vreg0, vreg1;
    float relc[16];
    kreg0 = *reinterpret_cast<const ushort8v*>(&Kbase[(size_t)r0 * HID_ + cc0 * 8]);
    kreg1 = *reinterpret_cast<const ushort8v*>(&Kbase[(size_t)r1 * HID_ + cc1 * 8]);
    vreg0 = *reinterpret_cast<const ushort8v*>(&Vbase[(size_t)r0 * L_ + cc0 * 8]);
    vreg1 = *reinterpret_cast<const ushort8v*>(&Vbase[(size_t)r1 * L_ + cc1 * 8]);
#pragma unroll
    for (int ni = 0; ni < 4; ++ni)
#pragma unroll
        for (int r = 0; r < 4; ++r)
            relc[ni * 4 + r] = relbase[(size_t)r * L_ + ni * 16];

    int cur = 0;
    for (int kt = 0; kt < nkt; ++kt) {
        const int k0 = kt * 64;

        // write staged K/V regs into LDS[cur]
        *reinterpret_cast<ushort8v*>(&Ks[cur][r0 * 72 + cc0 * 8]) = kreg0;
        *reinterpret_cast<ushort8v*>(&Ks[cur][r1 * 72 + cc1 * 8]) = kreg1;
        *reinterpret_cast<ushort8v*>(&Vs[cur][r0 * 72 + cc0 * 8]) = vreg0;
        *reinterpret_cast<ushort8v*>(&Vs[cur][r1 * 72 + cc1 * 8]) = vreg1;
        __syncthreads();

        // issue next tile's global loads (hidden under this tile's compute)
        float reln[16];
        if (kt + 1 < nkt) {
            const int k0n = k0 + 64;
            kreg0 = *reinterpret_cast<const ushort8v*>(&Kbase[(size_t)(k0n + r0) * HID_ + cc0 * 8]);
            kreg1 = *reinterpret_cast<const ushort8v*>(&Kbase[(size_t)(k0n + r1) * HID_ + cc1 * 8]);
            vreg0 = *reinterpret_cast<const ushort8v*>(&Vbase[(size_t)r0 * L_ + k0n + cc0 * 8]);
            vreg1 = *reinterpret_cast<const ushort8v*>(&Vbase[(size_t)r1 * L_ + k0n + cc1 * 8]);
#pragma unroll
            for (int ni = 0; ni < 4; ++ni)
#pragma unroll
                for (int r = 0; r < 4; ++r)
                    reln[ni * 4 + r] = relbase[(size_t)r * L_ + k0n + ni * 16];
        }

        // S strip = Q strip @ K^T
        f32x4 s[4];
#pragma unroll
        for (int ni = 0; ni < 4; ++ni) s[ni] = (f32x4){0.f, 0.f, 0.f, 0.f};
#pragma unroll
        for (int ks = 0; ks < 2; ++ks) {
#pragma unroll
            for (int ni = 0; ni < 4; ++ni) {
                bf16x8 bk = *reinterpret_cast<const bf16x8*>(
                    &Ks[cur][(ni * 16 + lq) * 72 + ks * 32 + g * 8]);
                s[ni] = __builtin_amdgcn_mfma_f32_16x16x32_bf16(aq[ks], bk, s[ni], 0, 0, 0);
            }
        }

        // + rel bias (prefetched), mask
        float sv[4][4];
#pragma unroll
        for (int ni = 0; ni < 4; ++ni) {
            const int col = k0 + ni * 16 + lq;
            const bool ok = col < sl;
#pragma unroll
            for (int r = 0; r < 4; ++r)
                sv[ni][r] = ok ? (s[ni][r] + relc[ni * 4 + r]) : NEGV;
        }

        // online softmax per row (16 lanes share a row)
#pragma unroll
        for (int r = 0; r < 4; ++r) {
            float rm = fmaxf(fmaxf(sv[0][r], sv[1][r]), fmaxf(sv[2][r], sv[3][r]));
            rm = fmaxf(rm, __shfl_xor(rm, 1, 16));
            rm = fmaxf(rm, __shfl_xor(rm, 2, 16));
            rm = fmaxf(rm, __shfl_xor(rm, 4, 16));
            rm = fmaxf(rm, __shfl_xor(rm, 8, 16));
            float mn = fmaxf(m_r[r], rm);
            float sc = __expf(m_r[r] - mn);
            float p[4], rs = 0.f;
#pragma unroll
            for (int ni = 0; ni < 4; ++ni) {
                p[ni] = __expf(sv[ni][r] - mn);
                rs += p[ni];
            }
            rs += __shfl_xor(rs, 1, 16);
            rs += __shfl_xor(rs, 2, 16);
            rs += __shfl_xor(rs, 4, 16);
            rs += __shfl_xor(rs, 8, 16);
            l_r[r] = l_r[r] * sc + rs;
            m_r[r] = mn;
#pragma unroll
            for (int ni = 0; ni < 4; ++ni) {
                acc[ni][r] *= sc;
                Ps[(w * 16 + 4 * g + r) * 72 + ni * 16 + lq] = f2bf(p[ni]);
            }
        }

        // O strip += P strip @ V tile (own-wave strip, no barrier needed)
#pragma unroll
        for (int ks = 0; ks < 2; ++ks) {
            bf16x8 ap = *reinterpret_cast<const bf16x8*>(
                &Ps[(w * 16 + lq) * 72 + ks * 32 + g * 8]);
#pragma unroll
            for (int ni = 0; ni < 4; ++ni) {
                bf16x8 bv = *reinterpret_cast<const bf16x8*>(
                    &Vs[cur][(ni * 16 + lq) * 72 + ks * 32 + g * 8]);
                acc[ni] = __builtin_amdgcn_mfma_f32_16x16x32_bf16(ap, bv, acc[ni], 0, 0, 0);
            }
        }

        // carry prefetched rel into current slot
#pragma unroll
        for (int i = 0; i < 16; ++i) relc[i] = reln[i];
        cur ^= 1;
    }

    // epilogue
    float inv[4];
#pragma unroll
    for (int r = 0; r < 4; ++r) inv[r] = 1.f / l_r[r];
#pragma unroll
    for (int ni = 0; ni < 4; ++ni)
#pragma unroll
        for (int r = 0; r < 4; ++r)
            ctx[(size_t)(b * L_ + q0 + w * 16 + 4 * g + r) * HID_ + h * D_ + ni * 16 + lq] =
                f2bf(acc[ni][r] * inv[r]);
}

// ---------------------------------------------------------------------------
// LayerNorm(2*x) over rows of 768; out f32 or bf16.
// ---------------------------------------------------------------------------
__global__ __launch_bounds__(256) void ln2_kernel(
    const float* __restrict__ in, const float* __restrict__ g,
    const float* __restrict__ bta, void* __restrict__ out, int bf16out)
{
    const int row = blockIdx.x;
    const float* x = in + (size_t)row * HID_;
    const int tid = threadIdx.x;

    float vals[3];
    float s = 0.f, ss = 0.f;
#pragma unroll
    for (int j = 0; j < 3; ++j) {
        float t = 2.f * x[tid + j * 256];
        vals[j] = t;
        s += t;
        ss += t * t;
    }
#pragma unroll
    for (int m = 1; m < 64; m <<= 1) {
        s += __shfl_xor(s, m, 64);
        ss += __shfl_xor(ss, m, 64);
    }
    __shared__ float sb[4], ssb[4];
    if ((tid & 63) == 0) { sb[tid >> 6] = s; ssb[tid >> 6] = ss; }
    __syncthreads();
    s = sb[0] + sb[1] + sb[2] + sb[3];
    ss = ssb[0] + ssb[1] + ssb[2] + ssb[3];
    const float mean = s * (1.f / 768.f);
    float var = ss * (1.f / 768.f) - mean * mean;
    if (var < 0.f) var = 0.f;
    const float invs = rsqrtf(var + 1e-5f);
    if (bf16out) {
        unsigned short* o = (unsigned short*)out;
#pragma unroll
        for (int j = 0; j < 3; ++j) {
            int c = tid + j * 256;
            o[(size_t)row * HID_ + c] = f2bf((vals[j] - mean) * invs * g[c] + bta[c]);
        }
    } else {
        float* o = (float*)out;
#pragma unroll
        for (int j = 0; j < 3; ++j) {
            int c = tid + j * 256;
            o[(size_t)row * HID_ + c] = (vals[j] - mean) * invs * g[c] + bta[c];
        }
    }
}

// ---------------------------------------------------------------------------
extern "C" void kernel_launch(void* const* d_in, const int* in_sizes, int n_in,
                              void* d_out, int out_size, void* d_ws, size_t ws_size,
                              hipStream_t stream) {
    const float* inp     = (const float*)d_in[0];
    const int*   seq_len = (const int*)d_in[1];
    const int*   lex_num = (const int*)d_in[2];
    const float* rel     = (const float*)d_in[3];
    const float* Wq = (const float*)d_in[4];
    const float* bq = (const float*)d_in[5];
    const float* Wk = (const float*)d_in[6];
    const float* bk = (const float*)d_in[7];
    const float* Wv = (const float*)d_in[8];
    const float* bv = (const float*)d_in[9];
    const float* Wo = (const float*)d_in[10];
    const float* bo = (const float*)d_in[11];
    const float* W0 = (const float*)d_in[12];
    const float* b0 = (const float*)d_in[13];
    const float* W1 = (const float*)d_in[14];
    const float* b1 = (const float*)d_in[15];
    const float* ln_g = (const float*)d_in[16];
    const float* ln_b = (const float*)d_in[17];
    float* out = (float*)d_out;

    // ---- workspace carve (bytes) ----
    char* W = (char*)d_ws;
    const size_t WT_SZ = (size_t)HID_ * HID_ * 2;
    unsigned short* Wt[6];
    for (int i = 0; i < 6; ++i) Wt[i] = (unsigned short*)(W + i * WT_SZ);
    size_t off = 6 * WT_SZ;
    const size_t TOK_BF = (size_t)B_ * L_ * HID_ * 2;
    unsigned short* qb  = (unsigned short*)(W + off); off += TOK_BF;
    unsigned short* kb  = (unsigned short*)(W + off); off += TOK_BF;
    unsigned short* vtb = (unsigned short*)(W + off); off += TOK_BF;
    unsigned short* Eb  = (unsigned short*)(W + off); off += TOK_BF;
    float* Fbuf = (float*)(W + off);

    unsigned short* Xb   = Eb;
    unsigned short* ctxb = Eb;
    unsigned short* y2b  = vtb;
    unsigned short* hb   = qb;

    convert_x_kernel<<<dim3(3072), dim3(256), 0, stream>>>(inp, Xb, (B_ * L_ * HID_) / 4);

    {
        WArgs wa;
        const float* ws_[6] = {Wq, Wk, Wv, Wo, W0, W1};
        for (int i = 0; i < 6; ++i) { wa.w[i] = ws_[i]; wa.wt[i] = Wt[i]; }
        transpose_w_kernel<<<dim3(12, 12, 6), dim3(256), 0, stream>>>(wa);
    }

    {
        GemmArgs ga;
        ga.j[0] = {Xb, Wt[0], bq, (void*)qb,  1, 0, SCALE_};
        ga.j[1] = {Xb, Wt[1], bk, (void*)kb,  1, 0, 1.f};
        ga.j[2] = {Xb, Wt[2], bv, (void*)vtb, 2, 0, 1.f};
        gemm_bf16_kernel<<<dim3(32, 6, 3), dim3(256), 0, stream>>>(ga);
    }

    attn_mfma_kernel<<<dim3(16, 48), dim3(256), 0, stream>>>(
        qb, kb, vtb, rel, seq_len, lex_num, ctxb);

    {
        GemmArgs ga;
        ga.j[0] = {ctxb, Wt[3], bo, (void*)Fbuf, 0, 0, 1.f};
        gemm_bf16_kernel<<<dim3(32, 6, 1), dim3(256), 0, stream>>>(ga);
    }
    ln2_kernel<<<dim3(4096), dim3(256), 0, stream>>>(Fbuf, ln_g, ln_b, (void*)y2b, 1);
    {
        GemmArgs ga;
        ga.j[0] = {y2b, Wt[4], b0, (void*)hb, 1, 1, 1.f};
        gemm_bf16_kernel<<<dim3(32, 6, 1), dim3(256), 0, stream>>>(ga);
    }
    {
        GemmArgs ga;
        ga.j[0] = {hb, Wt[5], b1, (void*)Fbuf, 0, 0, 1.f};
        gemm_bf16_kernel<<<dim3(32, 6, 1), dim3(256), 0, stream>>>(ga);
    }
    ln2_kernel<<<dim3(4096), dim3(256), 0, stream>>>(Fbuf, ln_g, ln_b, (void*)out, 0);
}